// Round 4
// baseline (788.457 us; speedup 1.0000x reference)
//
#include <hip/hip_runtime.h>
#include <hip/hip_cooperative_groups.h>

namespace cg = cooperative_groups;

#define N_NODES 10000
#define N_EDGES 640000
#define D 128
#define BN_EPS 1e-5f
#define TM 32
#define NPAD 10240   // 256 threads * 40 items in scan
#define GRID_COOP 512

// =====================================================================
// Fused single-dispatch cooperative kernel
// Phases: zero -> hist -> scan -> fill -> gather -> mlp(+stats) -> bn
// =====================================================================
__global__ __launch_bounds__(256) void k_fused(
    const float* __restrict__ x,
    const int*   __restrict__ ei,
    const float* __restrict__ W,
    const float* __restrict__ bias,
    const float* __restrict__ gamma,
    const float* __restrict__ beta,
    float* __restrict__ out,
    float* __restrict__ pre,
    float* __restrict__ stats,
    int* __restrict__ deg,
    int* __restrict__ offs,
    int* __restrict__ cursor,
    int* __restrict__ ssrc)
{
    cg::grid_group grid = cg::this_grid();
    __shared__ float Ws[64 * D];     // 32 KB: half of W (mlp phase)
    __shared__ float hs[TM][D + 4];  // 16.9 KB: row tile (mlp) / scan scratch
    const int tid  = threadIdx.x;
    const int gtid = blockIdx.x * 256 + tid;
    const int nthr = gridDim.x * 256;

    // ---- P0: zero deg + stats (ws is poisoned 0xAA before every call) ----
    for (int i = gtid; i < NPAD; i += nthr) deg[i] = 0;
    if (gtid < 2 * D) stats[gtid] = 0.f;
    __threadfence();
    grid.sync();

    // ---- P1: degree histogram ----
    for (int e = gtid; e < N_EDGES; e += nthr)
        atomicAdd(&deg[ei[N_EDGES + e]], 1);
    __threadfence();
    grid.sync();

    // ---- P2: exclusive scan (block 0 only) ----
    if (blockIdx.x == 0) {
        int* part = (int*)&hs[0][0];
        const int base = tid * 40;
        int local[40];
        int sum = 0;
        #pragma unroll
        for (int i = 0; i < 40; i++) { local[i] = deg[base + i]; sum += local[i]; }
        part[tid] = sum;
        __syncthreads();
        for (int off = 1; off < 256; off <<= 1) {
            int add = (tid >= off) ? part[tid - off] : 0;
            __syncthreads();
            part[tid] += add;
            __syncthreads();
        }
        int run = (tid == 0) ? 0 : part[tid - 1];
        #pragma unroll
        for (int i = 0; i < 40; i++) {
            offs[base + i] = run;
            cursor[base + i] = run;
            run += local[i];
        }
    }
    __threadfence();
    grid.sync();

    // ---- P3: scatter src ids into CSR order ----
    for (int e = gtid; e < N_EDGES; e += nthr) {
        const int pos = atomicAdd(&cursor[ei[N_EDGES + e]], 1);
        ssrc[pos] = ei[e];
    }
    __threadfence();
    grid.sync();

    // ---- P4: gather-sum, 1 wave/node, paired-float4 row loads ----
    {
        const float4* __restrict__ x4 = (const float4*)x;
        float4* pre4 = (float4*)pre;
        const int wid  = gtid >> 6;
        const int nw   = nthr >> 6;
        const int lane = tid & 63;
        const int h = lane >> 5;   // half: 0 = even edges, 1 = odd edges
        const int l = lane & 31;   // owns cols 4l..4l+3
        for (int node = wid; node < N_NODES; node += nw) {
            const int off = offs[node];
            const int n   = deg[node];
            float4 acc = make_float4(0.f, 0.f, 0.f, 0.f);
            int i = 0;
            while (i < n) {
                const int c = (n - i < 64) ? (n - i) : 64;
                const int sj = (lane < c) ? ssrc[off + i + lane] : 0;
                int t = 0;
                #pragma unroll 8
                for (; 2 * t + 1 < c; t++) {
                    const int s = __shfl(sj, 2 * t + h, 64);
                    const float4 v = x4[(size_t)s * 32 + l];  // 2 rows / wave-instr
                    acc.x += v.x; acc.y += v.y; acc.z += v.z; acc.w += v.w;
                }
                if (c & 1) {
                    const int s = __shfl(sj, c - 1, 64);
                    if (h == 0) {
                        const float4 v = x4[(size_t)s * 32 + l];
                        acc.x += v.x; acc.y += v.y; acc.z += v.z; acc.w += v.w;
                    }
                }
                i += c;
            }
            // combine the two halves
            acc.x += __shfl_xor(acc.x, 32, 64);
            acc.y += __shfl_xor(acc.y, 32, 64);
            acc.z += __shfl_xor(acc.z, 32, 64);
            acc.w += __shfl_xor(acc.w, 32, 64);
            if (h == 0) {
                const float4 xv = x4[(size_t)node * 32 + l];  // fuse (1+eps)*x, eps=0
                float4 o;
                o.x = acc.x + xv.x; o.y = acc.y + xv.y;
                o.z = acc.z + xv.z; o.w = acc.w + xv.w;
                pre4[(size_t)node * 32 + l] = o;
            }
        }
    }
    __threadfence();
    grid.sync();

    // ---- P5: h = relu(pre @ W + b) -> out; BN stats via atomics ----
    for (int tile = blockIdx.x; tile * TM < N_NODES; tile += gridDim.x) {
        const int r0 = tile * TM;

        // Stage 32 rows of pre
        #pragma unroll
        for (int i = 0; i < 4; i++) {
            const int idx4 = tid + i * 256;
            const int row  = idx4 >> 5;
            const int c4   = (idx4 & 31) << 2;
            const int grow = r0 + row;
            float4 v = make_float4(0.f, 0.f, 0.f, 0.f);
            if (grow < N_NODES) v = *(const float4*)&pre[(size_t)grow * D + c4];
            *(float4*)&hs[row][c4] = v;
        }

        const int col = tid & 127;
        const int rg  = tid >> 7;
        float acc[16];
        #pragma unroll
        for (int i = 0; i < 16; i++) acc[i] = 0.f;

        for (int phase = 0; phase < 2; phase++) {
            __syncthreads();
            {
                float4* wd = (float4*)Ws;
                const float4* wsrc = (const float4*)&W[phase * 64 * D];
                #pragma unroll
                for (int i = 0; i < 8; i++)
                    wd[tid + i * 256] = wsrc[tid + i * 256];
            }
            __syncthreads();

            for (int kk = 0; kk < 64; kk += 4) {
                const int k = (phase << 6) + kk;
                const float w0 = Ws[(kk + 0) * D + col];
                const float w1 = Ws[(kk + 1) * D + col];
                const float w2 = Ws[(kk + 2) * D + col];
                const float w3 = Ws[(kk + 3) * D + col];
                #pragma unroll
                for (int i = 0; i < 16; i++) {
                    const float4 hv = *(const float4*)&hs[rg * 16 + i][k];  // broadcast
                    float a = acc[i];
                    a = fmaf(hv.x, w0, a);
                    a = fmaf(hv.y, w1, a);
                    a = fmaf(hv.z, w2, a);
                    a = fmaf(hv.w, w3, a);
                    acc[i] = a;
                }
            }
        }

        const float bcol = bias[col];
        float s1 = 0.f, s2 = 0.f;
        #pragma unroll
        for (int i = 0; i < 16; i++) {
            const int row = r0 + rg * 16 + i;
            if (row < N_NODES) {
                const float v = fmaxf(acc[i] + bcol, 0.f);
                out[(size_t)row * D + col] = v;
                s1 += v;
                s2 += v * v;
            }
        }

        __syncthreads();
        float* red = (float*)hs;
        red[tid]       = s1;
        red[256 + tid] = s2;
        __syncthreads();
        if (tid < D) {
            atomicAdd(&stats[tid],     red[tid]       + red[tid + 128]);
            atomicAdd(&stats[D + tid], red[256 + tid] + red[256 + tid + 128]);
        }
        __syncthreads();  // hs reused next tile (defensive; ≤1 tile at grid 512)
    }
    __threadfence();
    grid.sync();

    // ---- P6: BatchNorm apply in place on out ----
    for (int idx4 = gtid; idx4 < N_NODES * D / 4; idx4 += nthr) {
        const int base = idx4 << 2;
        const int c0 = base & (D - 1);
        float4 v = *(const float4*)&out[base];
        float vv[4] = { v.x, v.y, v.z, v.w };
        float o[4];
        #pragma unroll
        for (int j = 0; j < 4; j++) {
            const int c = c0 + j;
            const float mean = stats[c] * (1.0f / N_NODES);
            const float var  = stats[D + c] * (1.0f / N_NODES) - mean * mean;
            o[j] = (vv[j] - mean) * rsqrtf(var + BN_EPS) * gamma[c] + beta[c];
        }
        *(float4*)&out[base] = make_float4(o[0], o[1], o[2], o[3]);
    }
}

// =====================================================================
// Fallback path (round-3 proven pipeline) — used only if cooperative
// launch is rejected by the runtime.
// =====================================================================
__global__ __launch_bounds__(256) void k_hist(
    const int* __restrict__ ei, int* __restrict__ deg)
{
    const int e = blockIdx.x * 256 + threadIdx.x;
    atomicAdd(&deg[ei[N_EDGES + e]], 1);
}

__global__ __launch_bounds__(256) void k_scan(
    const int* __restrict__ deg, int* __restrict__ offs, int* __restrict__ cursor)
{
    __shared__ int part[256];
    const int tid = threadIdx.x;
    const int base = tid * 40;
    int local[40];
    int sum = 0;
    #pragma unroll
    for (int i = 0; i < 40; i++) { local[i] = deg[base + i]; sum += local[i]; }
    part[tid] = sum;
    __syncthreads();
    for (int off = 1; off < 256; off <<= 1) {
        int add = (tid >= off) ? part[tid - off] : 0;
        __syncthreads();
        part[tid] += add;
        __syncthreads();
    }
    int run = (tid == 0) ? 0 : part[tid - 1];
    #pragma unroll
    for (int i = 0; i < 40; i++) {
        offs[base + i] = run;
        cursor[base + i] = run;
        run += local[i];
    }
}

__global__ __launch_bounds__(256) void k_fill(
    const int* __restrict__ ei, int* __restrict__ cursor, int* __restrict__ ssrc)
{
    const int e = blockIdx.x * 256 + threadIdx.x;
    const int pos = atomicAdd(&cursor[ei[N_EDGES + e]], 1);
    ssrc[pos] = ei[e];
}

__global__ __launch_bounds__(256) void k_gather(
    const float* __restrict__ x,
    const int* __restrict__ offs,
    const int* __restrict__ deg,
    const int* __restrict__ ssrc,
    float* __restrict__ pre)
{
    const int node = blockIdx.x * 4 + (threadIdx.x >> 6);
    const int lane = threadIdx.x & 63;
    const int off = offs[node];
    const int n   = deg[node];
    const float2* __restrict__ x2 = (const float2*)x;

    float2 acc = make_float2(0.f, 0.f);
    int i = 0;
    for (; i + 64 <= n; i += 64) {
        const int sj = ssrc[off + i + lane];
        #pragma unroll 16
        for (int t = 0; t < 64; t++) {
            const int s = __shfl(sj, t);
            const float2 v = x2[(size_t)s * 64 + lane];
            acc.x += v.x; acc.y += v.y;
        }
    }
    const int rem = n - i;
    if (rem > 0) {
        const int sj = (lane < rem) ? ssrc[off + i + lane] : 0;
        for (int t = 0; t < rem; t++) {
            const int s = __shfl(sj, t);
            const float2 v = x2[(size_t)s * 64 + lane];
            acc.x += v.x; acc.y += v.y;
        }
    }
    const float2 xv = x2[(size_t)node * 64 + lane];
    acc.x += xv.x; acc.y += xv.y;
    ((float2*)pre)[(size_t)node * 64 + lane] = acc;
}

__global__ __launch_bounds__(256) void k_mlp(
    const float* __restrict__ pre,
    const float* __restrict__ W,
    const float* __restrict__ bias,
    float* __restrict__ hout,
    float* __restrict__ stats)
{
    __shared__ float Ws[64 * D];
    __shared__ float hs[TM][D + 4];
    const int tid = threadIdx.x;
    const int r0 = blockIdx.x * TM;

    #pragma unroll
    for (int i = 0; i < 4; i++) {
        const int idx4 = tid + i * 256;
        const int row  = idx4 >> 5;
        const int c4   = (idx4 & 31) << 2;
        const int grow = r0 + row;
        float4 v = make_float4(0.f, 0.f, 0.f, 0.f);
        if (grow < N_NODES) v = *(const float4*)&pre[(size_t)grow * D + c4];
        *(float4*)&hs[row][c4] = v;
    }

    const int col = tid & 127;
    const int rg  = tid >> 7;
    float acc[16];
    #pragma unroll
    for (int i = 0; i < 16; i++) acc[i] = 0.f;

    for (int phase = 0; phase < 2; phase++) {
        __syncthreads();
        {
            float4* wd = (float4*)Ws;
            const float4* wsrc = (const float4*)&W[phase * 64 * D];
            #pragma unroll
            for (int i = 0; i < 8; i++)
                wd[tid + i * 256] = wsrc[tid + i * 256];
        }
        __syncthreads();

        for (int kk = 0; kk < 64; kk += 4) {
            const int k = (phase << 6) + kk;
            const float w0 = Ws[(kk + 0) * D + col];
            const float w1 = Ws[(kk + 1) * D + col];
            const float w2 = Ws[(kk + 2) * D + col];
            const float w3 = Ws[(kk + 3) * D + col];
            #pragma unroll
            for (int i = 0; i < 16; i++) {
                const float4 hv = *(const float4*)&hs[rg * 16 + i][k];
                float a = acc[i];
                a = fmaf(hv.x, w0, a);
                a = fmaf(hv.y, w1, a);
                a = fmaf(hv.z, w2, a);
                a = fmaf(hv.w, w3, a);
                acc[i] = a;
            }
        }
    }

    const float bcol = bias[col];
    float s1 = 0.f, s2 = 0.f;
    #pragma unroll
    for (int i = 0; i < 16; i++) {
        const int row = r0 + rg * 16 + i;
        if (row < N_NODES) {
            const float v = fmaxf(acc[i] + bcol, 0.f);
            hout[(size_t)row * D + col] = v;
            s1 += v;
            s2 += v * v;
        }
    }

    __syncthreads();
    float* red = (float*)hs;
    red[tid]       = s1;
    red[256 + tid] = s2;
    __syncthreads();
    if (tid < D) {
        atomicAdd(&stats[tid],     red[tid]       + red[tid + 128]);
        atomicAdd(&stats[D + tid], red[256 + tid] + red[256 + tid + 128]);
    }
}

__global__ __launch_bounds__(256) void k_bn(
    float* hout,
    const float* __restrict__ stats,
    const float* __restrict__ gamma,
    const float* __restrict__ beta)
{
    const int idx4 = blockIdx.x * 256 + threadIdx.x;
    const int base = idx4 << 2;
    const int c0 = base & (D - 1);
    float4 v = *(const float4*)&hout[base];
    float vv[4] = { v.x, v.y, v.z, v.w };
    float o[4];
    #pragma unroll
    for (int j = 0; j < 4; j++) {
        const int c = c0 + j;
        const float mean = stats[c] * (1.0f / N_NODES);
        const float var  = stats[D + c] * (1.0f / N_NODES) - mean * mean;
        o[j] = (vv[j] - mean) * rsqrtf(var + BN_EPS) * gamma[c] + beta[c];
    }
    *(float4*)&hout[base] = make_float4(o[0], o[1], o[2], o[3]);
}

extern "C" void kernel_launch(void* const* d_in, const int* in_sizes, int n_in,
                              void* d_out, int out_size, void* d_ws, size_t ws_size,
                              hipStream_t stream)
{
    const float* x     = (const float*)d_in[0];  // [10000,128] fp32
    const int*   ei    = (const int*)d_in[1];    // [2,640000] int32
    const float* W     = (const float*)d_in[2];  // [128,128] fp32
    const float* bias  = (const float*)d_in[3];  // [128] fp32
    const float* gamma = (const float*)d_in[4];  // [128] fp32
    const float* beta  = (const float*)d_in[5];  // [128] fp32
    float* out = (float*)d_out;                  // [10000,128] fp32

    // Workspace: [pre 5.12MB][stats 1KB][deg 40KB][offs 40KB][cursor 40KB][ssrc 2.56MB]
    float* pre    = (float*)d_ws;
    float* stats  = pre + (size_t)N_NODES * D;
    int*   deg    = (int*)(stats + 2 * D);
    int*   offs   = deg + NPAD;
    int*   cursor = offs + NPAD;
    int*   ssrc   = cursor + NPAD;

    void* args[] = { (void*)&x, (void*)&ei, (void*)&W, (void*)&bias,
                     (void*)&gamma, (void*)&beta, (void*)&out,
                     (void*)&pre, (void*)&stats, (void*)&deg,
                     (void*)&offs, (void*)&cursor, (void*)&ssrc };
    hipError_t err = hipLaunchCooperativeKernel((const void*)k_fused,
                                                dim3(GRID_COOP), dim3(256),
                                                args, 0, stream);
    if (err != hipSuccess) {
        // Fallback: proven round-3 multi-dispatch pipeline
        hipMemsetAsync(stats, 0, (2 * D + NPAD) * sizeof(int), stream);
        k_hist<<<N_EDGES / 256, 256, 0, stream>>>(ei, deg);
        k_scan<<<1, 256, 0, stream>>>(deg, offs, cursor);
        k_fill<<<N_EDGES / 256, 256, 0, stream>>>(ei, cursor, ssrc);
        k_gather<<<N_NODES / 4, 256, 0, stream>>>(x, offs, deg, ssrc, pre);
        k_mlp<<<(N_NODES + TM - 1) / TM, 256, 0, stream>>>(pre, W, bias, out, stats);
        k_bn<<<(N_NODES * D) / (4 * 256), 256, 0, stream>>>(out, stats, gamma, beta);
    }
}